// Round 9
// baseline (421.336 us; speedup 1.0000x reference)
//
#include <hip/hip_runtime.h>
#include <stdint.h>

// ---------------------------------------------------------------------------
// LinearBlockSparseAttention on MI355X (gfx950) — round 8 (resubmit; R8 never
// ran: GPU acquisition timeout)
// R8 vs R7: K-loop rebuilt as BK=32 with 4-buffer LDS rotation (same 128 KB):
// stage(t+3) issued at tile t -> 3 tiles of prefetch depth (R4-R7 had ~0.5;
// loop was staging-latency-bound at 35% MfmaUtil). One barrier/tile, counted
// vmcnt(8) ledger, single scheduling region (R5 lesson). 64B-row bank-even
// swizzle slot^=(r&3)^((r>>2)&1) with pre-swizzled global source.
// Prologue kernels fused into one block-partitioned prep_k.
// ---------------------------------------------------------------------------

typedef unsigned short u16;
typedef __attribute__((ext_vector_type(4))) float f32x4;
typedef __attribute__((ext_vector_type(8))) __bf16 bf16x8;
typedef __attribute__((ext_vector_type(8))) u16 us8;
typedef __attribute__((ext_vector_type(4))) u16 us4;

#define GLOAD_LDS16(g, l)                                                      \
  __builtin_amdgcn_global_load_lds(                                            \
      (const __attribute__((address_space(1))) void*)(g),                      \
      (__attribute__((address_space(3))) void*)(l), 16, 0, 0)

__device__ __forceinline__ u16 f2bf(float f) {
  union { float f; unsigned u; } x; x.f = f;
  return (u16)((x.u + 0x7fffu + ((x.u >> 16) & 1u)) >> 16);
}

__device__ __forceinline__ bf16x8 ld8(const void* p) {
  return __builtin_bit_cast(bf16x8, *(const us8*)p);
}

__device__ __forceinline__ f32x4 mfma16(bf16x8 a, bf16x8 b, f32x4 c) {
  return __builtin_amdgcn_mfma_f32_16x16x32_bf16(a, b, c, 0, 0, 0);
}

// ---------------------------------------------------------------------------
// Fused prologue: block-partitioned {x cast | WvT | Wqp/Wkp | WoutT}.
__global__ __launch_bounds__(256)
void prep_k(const float* __restrict__ x, const float* __restrict__ Wqkv,
            const float* __restrict__ proj, const float* __restrict__ Wout,
            u16* __restrict__ xb, u16* __restrict__ wvT,
            u16* __restrict__ btqk, u16* __restrict__ woutT) {
  __shared__ __align__(16) float smem[8192 + 64];
  const int b = blockIdx.x, tid = threadIdx.x;

  if (b < 2048) {  // x -> bf16 (grid-stride over f32x4)
    const int stride = 2048 * 256;
    for (int i = b * 256 + tid; i < 4194304; i += stride) {
      f32x4 v = ((const f32x4*)x)[i];
      us4 o;
      o[0] = f2bf(v[0]); o[1] = f2bf(v[1]); o[2] = f2bf(v[2]); o[3] = f2bf(v[3]);
      ((us4*)xb)[i] = o;
    }
  } else if (b < 3072) {  // WvT: wvT[j][e] = Wqkv[e][2048+j]
    float (&tile)[32][33] = *reinterpret_cast<float (*)[32][33]>(smem);
    const int idx = b - 2048;
    const int j0 = (idx & 31) * 32, e0 = (idx >> 5) * 32;
    const int tx = tid & 31, ty = tid >> 5;
#pragma unroll
    for (int i = 0; i < 32; i += 8)
      tile[ty + i][tx] = Wqkv[(size_t)(e0 + ty + i) * 3072 + 2048 + j0 + tx];
    __syncthreads();
#pragma unroll
    for (int i = 0; i < 32; i += 8)
      wvT[(size_t)(j0 + ty + i) * 1024 + e0 + tx] = f2bf(tile[tx][ty + i]);
  } else if (b < 3328) {  // btqk[n = h*256 + qk*128 + f][e] = Wq/k @ proj
    float (&pl)[64][128] = *reinterpret_cast<float (*)[64][128]>(smem);
    const int idx = b - 3072;
    const int ec = idx & 7, h = (idx >> 3) & 15, qk = idx >> 7;
    const float* ph = proj + (size_t)h * 8192;
    for (int i = tid; i < 2048; i += 256)
      ((f32x4*)&pl[0][0])[i] = ((const f32x4*)ph)[i];
    __syncthreads();
    const int e = ec * 128 + (tid >> 1);
    const int f0 = (tid & 1) * 64;
    float wrow[64];
    const float* src = Wqkv + (size_t)e * 3072 + qk * 1024 + h * 64;
#pragma unroll
    for (int i = 0; i < 16; ++i)
      *(f32x4*)&wrow[i * 4] = *(const f32x4*)&src[i * 4];
    u16* dst = btqk + (size_t)(h * 256 + qk * 128) * 1024 + e;
    for (int fg = 0; fg < 16; ++fg) {
      f32x4 acc = (f32x4){0.f, 0.f, 0.f, 0.f};
      const int f = f0 + fg * 4;
#pragma unroll
      for (int d = 0; d < 64; ++d) acc += wrow[d] * *(f32x4*)&pl[d][f];
#pragma unroll
      for (int u = 0; u < 4; ++u) dst[(size_t)(f + u) * 1024] = f2bf(acc[u]);
    }
  } else {  // WoutT
    float (&tile)[32][33] = *reinterpret_cast<float (*)[32][33]>(smem);
    const int idx = b - 3328;
    const int c0 = (idx & 31) * 32, r0 = (idx >> 5) * 32;
    const int tx = tid & 31, ty = tid >> 5;
#pragma unroll
    for (int i = 0; i < 32; i += 8)
      tile[ty + i][tx] = Wout[(size_t)(r0 + ty + i) * 1024 + c0 + tx];
    __syncthreads();
#pragma unroll
    for (int i = 0; i < 32; i += 8)
      woutT[(size_t)(c0 + ty + i) * 1024 + r0 + tx] = f2bf(tile[tx][ty + i]);
  }
}

// ---------------------------------------------------------------------------
// 256x256 GEMM, BK=32, 4-buffer LDS rotation (4 x 32 KB), 8 waves (2Mx4N).
// stage(t+3) at tile t (3-deep prefetch), vmcnt(8)+1 barrier per tile.
// Bank-even swizzle: 16B slot ^= (r&3)^((r>>2)&1), pre-swizzled global src.
// EPI 0: head-tile: elu+1 -> LDS bounce -> fused block attention (in-place v)
// EPI 1: o_f32 = x + bias  (direct 64B stores)
// EPI 2: o_bf16 = x        (bf16 via LDS bounce)
template <int EPI>
__global__ __launch_bounds__(512, 1)
void gemm4b_k(const u16* __restrict__ A, int lda,
              const u16* __restrict__ Bt, int ldb,
              const float* __restrict__ bias,
              u16* __restrict__ o_bf16, const u16* __restrict__ v_in,
              float* __restrict__ o_f32, int K, int ntx) {
  __shared__ __align__(16) char lds[131072];
  const int tid = threadIdx.x, lane = tid & 63, w = tid >> 6;
  const int wm = w >> 2, wn = w & 3;
  const int lr = lane & 15, lg = lane >> 4;
  const int cpx = (int)gridDim.x >> 3;
  const int bid = blockIdx.x;
  const int s = (bid & 7) * cpx + (bid >> 3);
  const int bxN = (s % ntx) * 256;
  const int byM = (s / ntx) * 256;
  const int nt = K >> 5;  // BK=32; nt expected >= 4

  // staging geometry: thread covers LDS byte tid*16 of each 8 KB half-tile
  // (row r_s = tid>>2, slot tid&3); source slot pre-swizzled by the read XOR.
  const int r_s = tid >> 2;
  const int scol = ((tid & 3) ^ ((r_s & 3) ^ ((r_s >> 2) & 1))) * 8;

  auto stage_tile = [&](int t) {
    const int kt = t * 32, bo = (t & 3) * 32768;
    GLOAD_LDS16(A + (size_t)(byM + r_s) * lda + kt + scol,
                lds + bo + w * 1024);
    GLOAD_LDS16(A + (size_t)(byM + 128 + r_s) * lda + kt + scol,
                lds + bo + 8192 + w * 1024);
    GLOAD_LDS16(Bt + (size_t)(bxN + r_s) * ldb + kt + scol,
                lds + bo + 16384 + w * 1024);
    GLOAD_LDS16(Bt + (size_t)(bxN + 128 + r_s) * ldb + kt + scol,
                lds + bo + 24576 + w * 1024);
  };

  f32x4 acc[8][4];
#pragma unroll
  for (int i = 0; i < 8; ++i)
#pragma unroll
    for (int j = 0; j < 4; ++j) acc[i][j] = (f32x4){0.f, 0.f, 0.f, 0.f};

  // prologue: tiles 0,1,2 staged (12 loads/wave); vmcnt(8) -> tile0 resident.
  stage_tile(0); stage_tile(1); stage_tile(2);
  asm volatile("s_waitcnt vmcnt(8)" ::: "memory");
  __builtin_amdgcn_s_barrier();

  for (int t = 0; t < nt; ++t) {
    if (t + 3 < nt) stage_tile(t + 3);  // target buf read in t-1: sealed
    const char* bufp = lds + (t & 3) * 32768;
    bf16x8 bfr[4];
#pragma unroll
    for (int nj = 0; nj < 4; ++nj) {
      const int rb = wn * 64 + nj * 16 + lr;
      bfr[nj] = ld8(bufp + 16384 + rb * 64 +
                    ((lg * 16) ^ ((((rb & 3) ^ ((rb >> 2) & 1))) << 4)));
    }
#pragma unroll
    for (int mi = 0; mi < 8; ++mi) {
      const int ra = wm * 128 + mi * 16 + lr;
      bf16x8 a = ld8(bufp + ra * 64 +
                     ((lg * 16) ^ ((((ra & 3) ^ ((ra >> 2) & 1))) << 4)));
#pragma unroll
      for (int nj = 0; nj < 4; ++nj)
        acc[mi][nj] = mfma16(a, bfr[nj], acc[mi][nj]);
    }
    // ledger: outstanding = stages of t+1,t+2,t+3 (12) -> vmcnt(8) = t+1 in.
    if (t < nt - 3)
      asm volatile("s_waitcnt vmcnt(8)" ::: "memory");
    else if (t == nt - 3)
      asm volatile("s_waitcnt vmcnt(4)" ::: "memory");
    else
      asm volatile("s_waitcnt vmcnt(0)" ::: "memory");
    __builtin_amdgcn_s_barrier();
  }

  // ---- epilogue -----------------------------------------------------------
  if (EPI == 1) {
#pragma unroll
    for (int mi = 0; mi < 8; ++mi)
#pragma unroll
      for (int nj = 0; nj < 4; ++nj) {
        const int col = bxN + wn * 64 + nj * 16 + lr;
        const float bia = bias[col];
#pragma unroll
        for (int rr = 0; rr < 4; ++rr) {
          const int row = byM + wm * 128 + mi * 16 + lg * 4 + rr;
          o_f32[(size_t)row * 1024 + col] = acc[mi][nj][rr] + bia;
        }
      }
    return;
  }

  const int hh = bxN >> 8;  // head index (EPI 0)

  // EPI 0: early v-tile loads (T14): 32 tokens x 64 cols per wave
  us8 vreg[4];
  if (EPI == 0) {
    const u16* vrow = v_in +
        (size_t)(byM + w * 32 + (lane >> 1)) * 1024 + hh * 64 + (lane & 1) * 32;
#pragma unroll
    for (int c = 0; c < 4; ++c) vreg[c] = *(const us8*)&vrow[c * 8];
  }

  u16* cl = (u16*)lds;  // [256 rows][512 B], XOR-swizzled by (row&7)<<4
#pragma unroll
  for (int mi = 0; mi < 8; ++mi)
#pragma unroll
    for (int nj = 0; nj < 4; ++nj)
#pragma unroll
      for (int rr = 0; rr < 4; ++rr) {
        const int rl = wm * 128 + mi * 16 + lg * 4 + rr;
        const int clm = wn * 64 + nj * 16 + lr;
        float xv = acc[mi][nj][rr];
        float v = (EPI == 0) ? (xv > 0.f ? xv + 1.f : __expf(xv)) : xv;
        *(u16*)((char*)cl + ((rl * 512 + clm * 2) ^ ((rl & 7) << 4))) = f2bf(v);
      }
  __syncthreads();

  if (EPI == 2) {
#pragma unroll
    for (int it = 0; it < 16; ++it) {
      const int chunk = it * 512 + tid;
      const int r = chunk >> 5, k = chunk & 31;
      us8 val = *(us8*)((char*)cl + ((r * 512 + k * 16) ^ ((r & 7) << 4)));
      *(us8*)&o_bf16[(size_t)(byM + r) * 1024 + bxN + k * 8] = val;
    }
    return;
  }

  // ---- EPI 0: fused block attention, one 32-token block per wave ----------
  char* sw = (char*)lds + w * 16384;

  // S = qf @ kf^T (32x32, K=128); qf = cols 0..127, kf = cols 128..255
  f32x4 sacc[2][2];
#pragma unroll
  for (int mm = 0; mm < 2; ++mm)
#pragma unroll
    for (int nn = 0; nn < 2; ++nn) sacc[mm][nn] = (f32x4){0.f, 0.f, 0.f, 0.f};
#pragma unroll
  for (int ks = 0; ks < 4; ++ks) {
    bf16x8 aq[2], bk[2];
#pragma unroll
    for (int mm = 0; mm < 2; ++mm) {
      const int row = mm * 16 + lr;
      aq[mm] = ld8(sw + ((row * 512 + ks * 64 + lg * 16) ^ ((row & 7) << 4)));
      bk[mm] = ld8(sw + ((row * 512 + 256 + ks * 64 + lg * 16) ^ ((row & 7) << 4)));
    }
#pragma unroll
    for (int mm = 0; mm < 2; ++mm)
#pragma unroll
      for (int nn = 0; nn < 2; ++nn)
        sacc[mm][nn] = mfma16(aq[mm], bk[nn], sacc[mm][nn]);
  }

  // row sums (z denominator)
  float rs[2][4];
#pragma unroll
  for (int mm = 0; mm < 2; ++mm)
#pragma unroll
    for (int r = 0; r < 4; ++r) {
      float tv = sacc[mm][0][r] + sacc[mm][1][r];
      tv += __shfl_xor(tv, 1);
      tv += __shfl_xor(tv, 2);
      tv += __shfl_xor(tv, 4);
      tv += __shfl_xor(tv, 8);
      rs[mm][r] = tv;
    }

  // S -> bf16 into sw[0..2047]
#pragma unroll
  for (int mm = 0; mm < 2; ++mm)
#pragma unroll
    for (int nn = 0; nn < 2; ++nn)
#pragma unroll
      for (int r = 0; r < 4; ++r) {
        const int row = mm * 16 + lg * 4 + r;
        *(u16*)(sw + row * 64 + (((nn * 16 + lr) * 2) ^ ((row & 3) << 4))) =
            f2bf(sacc[mm][nn][r]);
      }

  // V regs -> padded LDS at sw+2048 (stride 144 B), gather B-frags
#pragma unroll
  for (int c = 0; c < 4; ++c)
    *(us8*)(sw + 2048 + (lane >> 1) * 144 + (lane & 1) * 64 + c * 16) = vreg[c];
  const u16* V_l = (const u16*)(sw + 2048);  // stride 72 u16
  bf16x8 vfr[4];
#pragma unroll
  for (int nn = 0; nn < 4; ++nn) {
    us8 g;
#pragma unroll
    for (int j = 0; j < 8; ++j) g[j] = V_l[(lg * 8 + j) * 72 + nn * 16 + lr];
    vfr[nn] = __builtin_bit_cast(bf16x8, g);
  }

  // PV: out = S @ V (32x64, K=32)
  f32x4 pacc[2][4];
#pragma unroll
  for (int mm = 0; mm < 2; ++mm)
#pragma unroll
    for (int nn = 0; nn < 4; ++nn) pacc[mm][nn] = (f32x4){0.f, 0.f, 0.f, 0.f};
#pragma unroll
  for (int mm = 0; mm < 2; ++mm) {
    const int row = mm * 16 + lr;
    bf16x8 a = ld8(sw + row * 64 + ((lg * 16) ^ ((row & 3) << 4)));
#pragma unroll
    for (int nn = 0; nn < 4; ++nn) pacc[mm][nn] = mfma16(a, vfr[nn], pacc[mm][nn]);
  }

  // normalize -> bank-swizzled out-bounce -> coalesced 64B stores
#pragma unroll
  for (int mm = 0; mm < 2; ++mm)
#pragma unroll
    for (int r = 0; r < 4; ++r) {
      const float z = 1.f / (rs[mm][r] + 1e-8f);
      const int row = mm * 16 + lg * 4 + r;
#pragma unroll
      for (int nn = 0; nn < 4; ++nn)
        *(u16*)(sw + 8192 + row * 128 +
                (((nn * 16 + lr) * 2) ^ ((row & 7) << 4))) =
            f2bf(pacc[mm][nn][r] * z);
    }
  u16* orow = o_bf16 +
      (size_t)(byM + w * 32 + (lane >> 1)) * 1024 + hh * 64 + (lane & 1) * 32;
  const int vr = lane >> 1;
#pragma unroll
  for (int c = 0; c < 4; ++c)
    *(us8*)&orow[c * 8] =
        *(us8*)(sw + 8192 + vr * 128 +
                (((lane & 1) * 64 + c * 16) ^ ((vr & 7) << 4)));
}

// ---------------------------------------------------------------------------
extern "C" void kernel_launch(void* const* d_in, const int* in_sizes, int n_in,
                              void* d_out, int out_size, void* d_ws,
                              size_t ws_size, hipStream_t stream) {
  const float* x = (const float*)d_in[0];     // [4,4096,1024]
  const float* Wqkv = (const float*)d_in[1];  // [1024,3072]
  const float* proj = (const float*)d_in[2];  // [16,64,128]
  const float* Wout = (const float*)d_in[3];  // [1024,1024]
  const float* bout = (const float*)d_in[4];  // [1024]
  float* out = (float*)d_out;                 // [4,4096,1024] fp32

  char* ws = (char*)d_ws;
  char* doc = (char*)d_out;  // d_out as scratch: all dead before EPI1 writes

  u16* xb    = (u16*)doc;                   // 33,554,432 B  (x in bf16)
  u16* btqk  = (u16*)(doc + 33554432);      //  8,388,608 B  head-major [4096][1024]
  u16* wvT   = (u16*)(doc + 41943040);      //  2,097,152 B  [1024][1024]
  u16* vbuf  = (u16*)ws;                    // 33,554,432 B  v -> attn out (in-place)
  u16* woutT = (u16*)(ws + 33554432);       //  2,097,152 B

  prep_k<<<4352, 256, 0, stream>>>(x, Wqkv, proj, Wout, xb, wvT, btqk, woutT);

  // v = x @ Wv  (bf16 row-major into vbuf)
  gemm4b_k<2><<<256, 512, 0, stream>>>(xb, 1024, wvT, 1024, nullptr,
                                       vbuf, nullptr, nullptr, 1024, 4);

  // qf|kf GEMM + fused block attention (overwrites vbuf in place)
  gemm4b_k<0><<<1024, 512, 0, stream>>>(xb, 1024, btqk, 1024, nullptr,
                                        vbuf, vbuf, nullptr, 1024, 16);

  // y = attn @ Wout + bout
  gemm4b_k<1><<<256, 512, 0, stream>>>(vbuf, 1024, woutT, 1024, bout,
                                       nullptr, nullptr, out, 1024, 4);
}